// Round 1
// baseline (1176.395 us; speedup 1.0000x reference)
//
#include <hip/hip_runtime.h>
#include <math.h>

#define G_   8
#define NPG_ 4096
#define HC_  16
#define LAT_ 64
#define FF_  512
#define EDIM_ 3
#define EH_  64
#define NN_  32768
#define EE_  393216

// ---------------- front-end ----------------
// h1[8,512] = x[8,64] @ fc2_w[64,512] + fc2_b
__global__ void k_front1(const float* __restrict__ x, const float* __restrict__ w,
                         const float* __restrict__ b, float* __restrict__ h1) {
  int c = blockIdx.x * blockDim.x + threadIdx.x;
  if (c >= FF_) return;
  float acc[G_];
#pragma unroll
  for (int g = 0; g < G_; g++) acc[g] = 0.f;
  for (int r = 0; r < LAT_; r++) {
    float wv = w[r * FF_ + c];
#pragma unroll
    for (int g = 0; g < G_; g++) acc[g] = fmaf(x[g * LAT_ + r], wv, acc[g]);
  }
#pragma unroll
  for (int g = 0; g < G_; g++) h1[g * FF_ + c] = acc[g] + b[c];
}

// hn[N,16] = elu(h1[8,512] @ fc1_w[512,65536] + fc1_b), laid out node-major.
// Block: 512 threads = 8 waves; wave g handles row g, lanes cover 64 cols.
__global__ __launch_bounds__(512) void k_front2(const float* __restrict__ h1,
                                                const float* __restrict__ w,
                                                const float* __restrict__ b,
                                                float* __restrict__ hn) {
  __shared__ float sh[G_ * FF_];
  for (int i = threadIdx.x; i < G_ * FF_; i += blockDim.x) sh[i] = h1[i];
  __syncthreads();
  int g = threadIdx.x >> 6;
  int lane = threadIdx.x & 63;
  int c = blockIdx.x * 64 + lane;
  const float* shg = &sh[g * FF_];
  float acc = 0.f;
#pragma unroll 8
  for (int r = 0; r < FF_; r++) acc = fmaf(shg[r], w[r * (NPG_ * HC_) + c], acc);
  float v = acc + b[c];
  // node n = g*4096 + (c>>4); hn[n*16 + (c&15)] == hn[g*65536 + c]
  hn[g * (NPG_ * HC_) + c] = v > 0.f ? v : expm1f(v);
}

// ---------------- counting sort by src ----------------
__global__ void k_zero(int* __restrict__ p, int nv) {
  int i = blockIdx.x * blockDim.x + threadIdx.x;
  if (i < nv) p[i] = 0;
}
__global__ void k_hist(const int* __restrict__ src, int* __restrict__ cnt) {
  int e = blockIdx.x * blockDim.x + threadIdx.x;
  if (e < EE_) atomicAdd(&cnt[src[e]], 1);
}
// single block of 1024 threads, each owns 32 consecutive counts
__global__ __launch_bounds__(1024) void k_scan(const int* __restrict__ cnt,
                                               int* __restrict__ rowptr,
                                               int* __restrict__ cursor) {
  __shared__ int part[1024];
  int t = threadIdx.x;
  int base = t * 32;
  int loc[32];
  int s = 0;
#pragma unroll
  for (int i = 0; i < 32; i++) { loc[i] = s; s += cnt[base + i]; }
  part[t] = s;
  __syncthreads();
  for (int off = 1; off < 1024; off <<= 1) {
    int v = (t >= off) ? part[t - off] : 0;
    __syncthreads();
    part[t] += v;
    __syncthreads();
  }
  int pre = (t == 0) ? 0 : part[t - 1];
#pragma unroll
  for (int i = 0; i < 32; i++) {
    int v = pre + loc[i];
    rowptr[base + i] = v;
    cursor[base + i] = v;
  }
  if (t == 1023) rowptr[NN_] = part[1023];
}
__global__ void k_scatter(const int* __restrict__ src, int* __restrict__ cursor,
                          int* __restrict__ perm) {
  int e = blockIdx.x * blockDim.x + threadIdx.x;
  if (e < EE_) {
    int pos = atomicAdd(&cursor[src[e]], 1);
    perm[pos] = e;
  }
}

// ---------------- per-conv kernels ----------------
// hnext[n,o] = bias[o] + sum_i hn[n,i]*root[i,o]
__global__ void k_nodeinit(const float* __restrict__ hn, const float* __restrict__ root,
                           const float* __restrict__ bias, float* __restrict__ out) {
  int idx = blockIdx.x * blockDim.x + threadIdx.x;
  if (idx >= NN_ * HC_) return;
  int nd = idx >> 4, o = idx & 15;
  float acc = bias[o];
#pragma unroll
  for (int i = 0; i < 16; i++) acc = fmaf(hn[nd * 16 + i], root[i * 16 + o], acc);
  out[idx] = acc;
}

// Edge aggregation. One wave per source node (4 waves/block).
// Lane l: o = l&15, q = l>>4. Lane holds M[h=q*16+j][o] for j=0..15 where
//   M[h][o] = sum_i x_n[i] * w2[h*256 + i*16 + o]
// msg[o] = sum_h hidden[h]*M[h][o] + T[o],  T[o] = sum_i x_n[i]*b2[i*16+o]
__global__ __launch_bounds__(256, 2) void k_edge(
    const float* __restrict__ hn, const int* __restrict__ perm,
    const int* __restrict__ rowptr, const int* __restrict__ dst,
    const float* __restrict__ ea, const float* __restrict__ w1,
    const float* __restrict__ b1, const float* __restrict__ w2,
    const float* __restrict__ b2, float* __restrict__ hnext) {
  // sW2 logical layout: idx = o*1024 + i*64 + h  (o,i in [0,16), h in [0,64))
  // stored at idx ^ ((o&7)<<2) to spread the o-stride-4KB reads across banks.
  __shared__ float sW2[16 * 1024];
  int tid = threadIdx.x;
  for (int idx = tid; idx < 16384; idx += 256) {
    int o = idx >> 10, i = (idx >> 6) & 15, h = idx & 63;
    sW2[idx ^ ((o & 7) << 2)] = w2[h * 256 + i * 16 + o];
  }
  __syncthreads();

  int wave = tid >> 6, l = tid & 63;
  int o = l & 15, q = l >> 4;
  int n = blockIdx.x * 4 + wave;

  float xv[16];
#pragma unroll
  for (int i = 0; i < 16; i++) xv[i] = hn[n * 16 + i];

  float M[16];
#pragma unroll
  for (int j = 0; j < 16; j++) M[j] = 0.f;
  int sbase = o * 1024 + q * 16;
  int sw = (o & 7) << 2;
#pragma unroll
  for (int i = 0; i < 16; i++) {
    float xi = xv[i];
    int ib = sbase + i * 64;
#pragma unroll
    for (int j4 = 0; j4 < 4; j4++) {
      float4 v = *(const float4*)&sW2[(ib + j4 * 4) ^ sw];
      M[j4 * 4 + 0] = fmaf(xi, v.x, M[j4 * 4 + 0]);
      M[j4 * 4 + 1] = fmaf(xi, v.y, M[j4 * 4 + 1]);
      M[j4 * 4 + 2] = fmaf(xi, v.z, M[j4 * 4 + 2]);
      M[j4 * 4 + 3] = fmaf(xi, v.w, M[j4 * 4 + 3]);
    }
  }

  // per-lane edge-MLP weights for h = q*16 + j
  float w1r0[16], w1r1[16], w1r2[16], b1r[16];
#pragma unroll
  for (int j = 0; j < 16; j++) {
    int h = q * 16 + j;
    w1r0[j] = w1[h];
    w1r1[j] = w1[64 + h];
    w1r2[j] = w1[128 + h];
    b1r[j] = b1[h];
  }
  float T = 0.f;
#pragma unroll
  for (int i = 0; i < 16; i++) T = fmaf(xv[i], b2[i * 16 + o], T);

  int rs = rowptr[n], re = rowptr[n + 1];
  if (rs >= re) return;

  // software-pipelined edge loop
  int e_n = perm[rs];
  int d_n = dst[e_n];
  float a0_n = ea[e_n * 3], a1_n = ea[e_n * 3 + 1], a2_n = ea[e_n * 3 + 2];
  for (int k = rs; k < re; k++) {
    int d = d_n;
    float a0 = a0_n, a1 = a1_n, a2 = a2_n;
    if (k + 1 < re) {
      int e2 = perm[k + 1];
      e_n = e2;
      d_n = dst[e2];
      a0_n = ea[e2 * 3];
      a1_n = ea[e2 * 3 + 1];
      a2_n = ea[e2 * 3 + 2];
    }
    float p = 0.f;
#pragma unroll
    for (int j = 0; j < 16; j++) {
      float hd = fmaf(a0, w1r0[j], fmaf(a1, w1r1[j], fmaf(a2, w1r2[j], b1r[j])));
      hd = fmaxf(hd, 0.f);
      p = fmaf(hd, M[j], p);
    }
    p += __shfl_xor(p, 16);
    p += __shfl_xor(p, 32);
    if (l < 16) atomicAdd(&hnext[d * 16 + o], p + T);
  }
}

__global__ void k_elu(const float* __restrict__ in, float* __restrict__ out) {
  int idx = blockIdx.x * blockDim.x + threadIdx.x;
  if (idx >= NN_ * HC_) return;
  float v = in[idx];
  out[idx] = v > 0.f ? v : expm1f(v);
}

// ---------------- launch ----------------
extern "C" void kernel_launch(void* const* d_in, const int* in_sizes, int n_in,
                              void* d_out, int out_size, void* d_ws, size_t ws_size,
                              hipStream_t stream) {
  const float* x    = (const float*)d_in[0];
  const int*   ei   = (const int*)d_in[1];
  const float* ea   = (const float*)d_in[2];
  const float* fc2w = (const float*)d_in[3];
  const float* fc2b = (const float*)d_in[4];
  const float* fc1w = (const float*)d_in[5];
  const float* fc1b = (const float*)d_in[6];
  float* out = (float*)d_out;

  float* ws    = (float*)d_ws;
  float* h1    = ws;                       // 4096
  float* hnode = ws + 4096;                // N*16
  float* hnext = hnode + NN_ * HC_;        // N*16
  int* cnt     = (int*)(hnext + NN_ * HC_);// N
  int* rowptr  = cnt + NN_;                // N+1
  int* cursor  = rowptr + NN_ + 1;         // N
  int* perm    = cursor + NN_;             // E

  const int* src = ei;
  const int* dstp = ei + EE_;

  k_front1<<<2, 256, 0, stream>>>(x, fc2w, fc2b, h1);
  k_front2<<<1024, 512, 0, stream>>>(h1, fc1w, fc1b, hnode);

  k_zero<<<(NN_ + 255) / 256, 256, 0, stream>>>(cnt, NN_);
  k_hist<<<(EE_ + 255) / 256, 256, 0, stream>>>(src, cnt);
  k_scan<<<1, 1024, 0, stream>>>(cnt, rowptr, cursor);
  k_scatter<<<(EE_ + 255) / 256, 256, 0, stream>>>(src, cursor, perm);

  for (int cv = 0; cv < 2; cv++) {
    const float* root = (const float*)d_in[7 + cv * 6];
    const float* cb   = (const float*)d_in[8 + cv * 6];
    const float* w1   = (const float*)d_in[9 + cv * 6];
    const float* b1   = (const float*)d_in[10 + cv * 6];
    const float* w2   = (const float*)d_in[11 + cv * 6];
    const float* b2   = (const float*)d_in[12 + cv * 6];
    k_nodeinit<<<NN_ * HC_ / 256, 256, 0, stream>>>(hnode, root, cb, hnext);
    k_edge<<<NN_ / 4, 256, 0, stream>>>(hnode, perm, rowptr, dstp, ea, w1, b1, w2,
                                        b2, hnext);
    k_elu<<<NN_ * HC_ / 256, 256, 0, stream>>>(hnext, cv == 0 ? hnode : out);
  }
}